// Round 1
// baseline (133.900 us; speedup 1.0000x reference)
//
#include <hip/hip_runtime.h>
#include <hip/hip_bf16.h>

// Sum each consecutive group of 4 rows of a (N, C) fp32 matrix -> (N/4, C),
// and gather pids[::4] (written as float, since the harness reads the whole
// d_out buffer as float32).
//
// N = 65536, C = 2048 (but written generically via runtime sizes).

__global__ void feat_group4_sum_kernel(const float4* __restrict__ in,
                                       float4* __restrict__ out_feat,
                                       const int* __restrict__ pids,
                                       float* __restrict__ out_pids,
                                       int c4,        // C/4 (float4s per row)
                                       int total_v4)  // (N/4) * c4
{
    const int stride = gridDim.x * blockDim.x;
    for (int i = blockIdx.x * blockDim.x + threadIdx.x; i < total_v4; i += stride) {
        const int g = i / c4;          // output row (group index)
        const int c = i - g * c4;      // float4 column within row
        const float4* __restrict__ base = in + (size_t)g * 4 * c4 + c;
        float4 a = base[0];
        float4 b = base[c4];
        float4 d = base[2 * c4];
        float4 e = base[3 * c4];
        float4 s;
        s.x = (a.x + b.x) + (d.x + e.x);
        s.y = (a.y + b.y) + (d.y + e.y);
        s.z = (a.z + b.z) + (d.z + e.z);
        s.w = (a.w + b.w) + (d.w + e.w);
        out_feat[i] = s;
        if (c == 0) {
            out_pids[g] = (float)pids[(size_t)g * 4];
        }
    }
}

extern "C" void kernel_launch(void* const* d_in, const int* in_sizes, int n_in,
                              void* d_out, int out_size, void* d_ws, size_t ws_size,
                              hipStream_t stream) {
    const float* features = (const float*)d_in[0];
    const int*   pids     = (const int*)d_in[1];

    const int N = in_sizes[1];          // 65536 (pids has N elements)
    const int C = in_sizes[0] / N;      // 2048
    const int G = N / 4;                // 16384 output rows
    const int c4 = C / 4;               // 512 float4s per row
    const int total_v4 = G * c4;        // 8,388,608

    float* out_feat_f = (float*)d_out;
    float* out_pids_f = out_feat_f + (size_t)G * C;

    const int block = 256;
    int grid = (total_v4 + block - 1) / block;
    if (grid > 8192) grid = 8192;

    feat_group4_sum_kernel<<<grid, block, 0, stream>>>(
        (const float4*)features, (float4*)out_feat_f, pids, out_pids_f,
        c4, total_v4);
}

// Round 3
// 114.733 us; speedup vs baseline: 1.1671x; 1.1671x over previous
//
#include <hip/hip_runtime.h>
#include <hip/hip_bf16.h>

// Sum each consecutive group of 4 rows of a (N, C) fp32 matrix -> (N/4, C),
// and gather pids[::4] (written as float: the harness reads d_out flat as f32).
//
// N = 65536, C = 2048. Pure streaming: 537 MB read-once + 134 MB write-once,
// no reuse -> non-temporal hints, one output vec4 per thread, no loops.
// Note: __builtin_nontemporal_* requires a native clang vector type, not
// HIP_vector_type (float4) -- use ext_vector_type(4).

typedef float f32x4 __attribute__((ext_vector_type(4)));

__global__ void feat_group4_sum_kernel(const f32x4* __restrict__ in,
                                       f32x4* __restrict__ out_feat,
                                       int c4)  // C/4 vec4s per row
{
    const int c = blockIdx.x * blockDim.x + threadIdx.x;  // vec4 column
    const int g = blockIdx.y;                             // output row (group)
    if (c >= c4) return;

    const f32x4* __restrict__ base = in + (size_t)g * 4 * c4 + c;
    f32x4 a = __builtin_nontemporal_load(base);
    f32x4 b = __builtin_nontemporal_load(base + c4);
    f32x4 d = __builtin_nontemporal_load(base + 2 * c4);
    f32x4 e = __builtin_nontemporal_load(base + 3 * c4);
    f32x4 s = (a + b) + (d + e);
    __builtin_nontemporal_store(s, out_feat + (size_t)g * c4 + c);
}

__global__ void pids_gather_kernel(const int* __restrict__ pids,
                                   float* __restrict__ out_pids,
                                   int G)
{
    const int g = blockIdx.x * blockDim.x + threadIdx.x;
    if (g < G) {
        out_pids[g] = (float)pids[(size_t)g * 4];
    }
}

extern "C" void kernel_launch(void* const* d_in, const int* in_sizes, int n_in,
                              void* d_out, int out_size, void* d_ws, size_t ws_size,
                              hipStream_t stream) {
    const float* features = (const float*)d_in[0];
    const int*   pids     = (const int*)d_in[1];

    const int N = in_sizes[1];          // 65536 (pids has N elements)
    const int C = in_sizes[0] / N;      // 2048
    const int G = N / 4;                // 16384 output rows
    const int c4 = C / 4;               // 512 vec4s per row

    float* out_feat_f = (float*)d_out;
    float* out_pids_f = out_feat_f + (size_t)G * C;

    const int block = 256;
    dim3 grid((c4 + block - 1) / block, G, 1);   // (2, 16384)
    feat_group4_sum_kernel<<<grid, block, 0, stream>>>(
        (const f32x4*)features, (f32x4*)out_feat_f, c4);

    pids_gather_kernel<<<(G + block - 1) / block, block, 0, stream>>>(
        pids, out_pids_f, G);
}